// Round 8
// baseline (72.315 us; speedup 1.0000x reference)
//
#include <hip/hip_runtime.h>
#include <hip/hip_bf16.h>

typedef __attribute__((ext_vector_type(8))) short short8;
typedef __attribute__((ext_vector_type(4))) float f32x4;
typedef float f4a __attribute__((ext_vector_type(4), aligned(4)));  // align-4 float4

constexpr int NF = 169;
constexpr int NH = 128;

#define MFMA(a, b, c) __builtin_amdgcn_mfma_f32_16x16x32_bf16(a, b, c, 0, 0, 0)

__device__ inline unsigned short f2bf(float f) {
    union { __hip_bfloat16 h; unsigned short u; } c;
    c.h = __float2bfloat16(f);
    return c.u;
}

// Block barrier draining only the LDS pipe (all cross-wave deps here are LDS).
__device__ inline void block_sync_lds() {
    __builtin_amdgcn_sched_barrier(0);
    asm volatile("s_waitcnt lgkmcnt(0)" ::: "memory");
    __builtin_amdgcn_sched_barrier(0);
    __builtin_amdgcn_s_barrier();
    __builtin_amdgcn_sched_barrier(0);
}

// LDS map (78336 B, 2 blocks/CU):
//  [0, 65536):      pool_g[8][256][8] bf16  --after afrag reads aliased by--> h_g[16][256][8] bf16
//  [65536, 77824):  w1g[8][128][8] bf16
//  [77824, 78336):  b1s[128] f32
// 3 block barriers total; GEMM2 loop is barrier-free (transposed-C direct stores).
__global__ __launch_bounds__(256, 2) void fused_v8(
    const float* __restrict__ x,
    const float* __restrict__ w1,
    const float* __restrict__ b1,
    const float* __restrict__ w2,
    const float* __restrict__ b2,
    float* __restrict__ out)
{
    __shared__ __align__(16) char smem[78336];
    unsigned short* pool_g = (unsigned short*)smem;            // [8][256][8]
    unsigned short* h_g    = (unsigned short*)smem;            // [16][256][8]
    unsigned short* w1g    = (unsigned short*)(smem + 65536);  // [8][128][8]
    float*          b1s    = (float*)(smem + 77824);           // [128]

    const int tid  = threadIdx.x;
    const int wid  = tid >> 6;
    const int lane = tid & 63;
    const int lr   = lane & 15;
    const int hi   = lane >> 4;

    // ---------------- stage w1 -> w1g (bf16, k zero-padded 36->64), b1 -> b1s ----------------
    #pragma unroll
    for (int it = 0; it < 4; ++it) {
        const int idx = tid + it * 256;   // 0..1023 = n*8 + g
        const int n = idx >> 3, g = idx & 7;
        short8 pk;
        #pragma unroll
        for (int j = 0; j < 8; ++j) {
            const int k = g * 8 + j;
            pk[j] = (short)f2bf(k < 36 ? w1[n * 36 + k] : 0.0f);
        }
        *(short8*)(w1g + (g * 128 + n) * 8) = pk;
    }
    if (tid < 128) b1s[tid] = b1[tid];

    // ---------------- per-thread pooling of row (blk*256 + tid) ----------------
    const long row = (long)blockIdx.x * 256 + tid;
    const float* __restrict__ xr = x + row * NF;

    float f[169];
    #pragma unroll
    for (int i = 0; i < 42; ++i) {
        f4a v = *(const f4a*)(xr + i * 4);
        f[4*i+0] = v[0]; f[4*i+1] = v[1]; f[4*i+2] = v[2]; f[4*i+3] = v[3];
    }
    f[168] = xr[168];

    float pooled[36];
    #pragma unroll
    for (int i = 0; i < 6; ++i) {
        float cs[13];
        #pragma unroll
        for (int c = 0; c < 13; ++c) {
            float s = 0.0f;
            #pragma unroll
            for (int rr = 0; rr < 3; ++rr) {
                const int idx = (2 * i + rr) * 14 + c;   // compile-time
                if (idx < NF) s += f[idx];               // pad region = 0
            }
            cs[c] = s;
        }
        #pragma unroll
        for (int j = 0; j < 6; ++j) {
            const float s = cs[2*j] + cs[2*j+1] + cs[2*j+2];
            pooled[i * 6 + j] = fmaxf(s * (1.0f / 9.0f), 0.0f);
        }
    }

    // write pooled row to pool_g, k-groups of 8, zeros for k >= 36
    #pragma unroll
    for (int g = 0; g < 8; ++g) {
        short8 pk;
        #pragma unroll
        for (int j = 0; j < 8; ++j) {
            const int k = g * 8 + j;
            pk[j] = (k < 36) ? (short)f2bf(pooled[k]) : (short)0;
        }
        *(short8*)(pool_g + (g * 256 + tid) * 8) = pk;
    }
    block_sync_lds();   // (1) pool_g complete

    // ---------------- A1 fragments (wave's 4 m-tiles) + w2/b2 fragments to registers ----------------
    short8 afrag[4][2];
    #pragma unroll
    for (int mt = 0; mt < 4; ++mt)
        #pragma unroll
        for (int ks = 0; ks < 2; ++ks) {
            const int g = ks * 4 + hi;
            afrag[mt][ks] = *(const short8*)(pool_g + (g * 256 + wid * 64 + mt * 16 + lr) * 8);
        }

    const int nOt = (wid < 3) ? 3 : 2;   // ot = wid + 4t, 11 total
    short8 wfrag[3][4];
    f32x4  bias2v[3];                    // per-reg bias: o = (wid+4t)*16 + hi*4 + r
    #pragma unroll
    for (int t = 0; t < 3; ++t) {
        const int ot = wid + 4 * t;
        const int o  = ot * 16 + lr;
        const bool valid = (t < nOt) && (o < NF);
        #pragma unroll
        for (int ks = 0; ks < 4; ++ks) {
            short8 pk = {0, 0, 0, 0, 0, 0, 0, 0};
            if (valid) {
                const float* wp = w2 + o * NH + ks * 32 + hi * 8;
                #pragma unroll
                for (int j = 0; j < 8; ++j) pk[j] = (short)f2bf(wp[j]);
            }
            wfrag[t][ks] = pk;
        }
        #pragma unroll
        for (int r = 0; r < 4; ++r) {
            const int ob = ot * 16 + hi * 4 + r;
            bias2v[t][r] = (t < nOt && ob < NF) ? b2[ob] : 0.0f;
        }
    }
    block_sync_lds();   // (2) all a-frags read; pool region dead -> h_g may overwrite

    // ---------------- GEMM1: h = relu(pooled @ w1^T + b1), written to h_g ----------------
    short8 b1f[8][2];
    #pragma unroll
    for (int nt = 0; nt < 8; ++nt)
        #pragma unroll
        for (int ks = 0; ks < 2; ++ks) {
            const int g = ks * 4 + hi;
            b1f[nt][ks] = *(const short8*)(w1g + (g * 128 + nt * 16 + lr) * 8);
        }
    float bias1[8];
    #pragma unroll
    for (int nt = 0; nt < 8; ++nt) bias1[nt] = b1s[nt * 16 + lr];

    #pragma unroll
    for (int mt = 0; mt < 4; ++mt) {
        #pragma unroll
        for (int nt = 0; nt < 8; ++nt) {
            f32x4 c = {0.f, 0.f, 0.f, 0.f};
            c = MFMA(afrag[mt][0], b1f[nt][0], c);
            c = MFMA(afrag[mt][1], b1f[nt][1], c);
            const int g = 2 * nt + (lr >> 3);
            const int e = lr & 7;
            #pragma unroll
            for (int r = 0; r < 4; ++r) {
                const float v = fmaxf(c[r] + bias1[nt], 0.0f);
                const int rw = wid * 64 + mt * 16 + hi * 4 + r;
                h_g[(g * 256 + rw) * 8 + e] = (unsigned short)f2bf(v);
            }
        }
    }
    block_sync_lds();   // (3) h_g complete — read-only from here; NO more barriers

    // ---------------- GEMM2: transposed-C (wfrag as A, a2 as B), direct stores ----------------
    // D[m=o][n=batch]: lane (lr,hi) holds out[mt*16+lr][ot*16 + hi*4 + r], r=0..3.
    const long blkRowBase = (long)blockIdx.x * 256;
    #pragma unroll 2
    for (int mt = 0; mt < 16; ++mt) {
        short8 a2[4];
        #pragma unroll
        for (int ks = 0; ks < 4; ++ks) {
            const int g = ks * 4 + hi;
            a2[ks] = *(const short8*)(h_g + (g * 256 + mt * 16 + lr) * 8);
        }
        f32x4 acc[3];
        #pragma unroll
        for (int t = 0; t < 3; ++t) {
            f32x4 c = bias2v[t];                      // bias folded into C-in
            #pragma unroll
            for (int ks = 0; ks < 4; ++ks)
                c = MFMA(wfrag[t][ks], a2[ks], c);    // swapped operands -> transposed C
            acc[t] = c;
        }
        float* oprow = out + (blkRowBase + mt * 16 + lr) * NF;
        #pragma unroll
        for (int t = 0; t < 3; ++t) {
            if (t < nOt) {
                const int ob = (wid + 4 * t) * 16 + hi * 4;
                #pragma unroll
                for (int r = 0; r < 4; ++r) {
                    const int o = ob + r;
                    if (o < NF) oprow[o] = acc[t][r];
                }
            }
        }
    }
}

extern "C" void kernel_launch(void* const* d_in, const int* in_sizes, int n_in,
                              void* d_out, int out_size, void* d_ws, size_t ws_size,
                              hipStream_t stream) {
    const float* x  = (const float*)d_in[0];
    const float* w1 = (const float*)d_in[1];
    const float* b1 = (const float*)d_in[2];
    const float* w2 = (const float*)d_in[3];
    const float* b2 = (const float*)d_in[4];
    float* out = (float*)d_out;

    const int rows = in_sizes[0] / NF;      // 131072
    const int blocks = rows / 256;          // 512
    fused_v8<<<blocks, 256, 0, stream>>>(x, w1, b1, w2, b2, out);
}

// Round 9
// 59.776 us; speedup vs baseline: 1.2098x; 1.2098x over previous
//
#include <hip/hip_runtime.h>
#include <hip/hip_bf16.h>

typedef __attribute__((ext_vector_type(8))) short short8;
typedef __attribute__((ext_vector_type(4))) float f32x4;
typedef __attribute__((ext_vector_type(2))) unsigned int uint2v;
typedef float f4a __attribute__((ext_vector_type(4), aligned(4)));

constexpr int NF = 169;
constexpr int NH = 128;

#define MFMA(a, b, c) __builtin_amdgcn_mfma_f32_16x16x32_bf16(a, b, c, 0, 0, 0)

__device__ inline unsigned short f2bf(float f) {
    union { __hip_bfloat16 h; unsigned short u; } c;
    c.h = __float2bfloat16(f);
    return c.u;
}
__device__ inline float bf2f(unsigned short u) {
    union { unsigned int u; float f; } c;
    c.u = ((unsigned int)u) << 16;
    return c.f;
}

// Block barrier draining only the LDS pipe (all cross-wave deps here are LDS;
// global stores stay in flight — no vmcnt drain).
__device__ inline void block_sync_lds() {
    __builtin_amdgcn_sched_barrier(0);
    asm volatile("s_waitcnt lgkmcnt(0)" ::: "memory");
    __builtin_amdgcn_sched_barrier(0);
    __builtin_amdgcn_s_barrier();
    __builtin_amdgcn_sched_barrier(0);
}

// LDS map (78336 B, 2 blocks/CU):
//  region A [0, 65536): during pooling: pool_g[8][256][8] bf16 at [0,32768)
//                       + xt[64*169] bf16 at [32768, 54400)
//                       after afrag reads: h_g[16][256][8] bf16 (full 64K)
//  region C [65536, 77824): w1g[8][128][8] bf16; stage[16][169] f32 aliases after GEMM1
//  region D [77824, 78336): b1s[128] f32
__global__ __launch_bounds__(256, 2) void fused_v9(
    const float* __restrict__ x,
    const float* __restrict__ w1,
    const float* __restrict__ b1,
    const float* __restrict__ w2,
    const float* __restrict__ b2,
    float* __restrict__ out)
{
    __shared__ __align__(16) char smem[78336];
    unsigned short* pool_g = (unsigned short*)smem;            // [8][256][8]
    unsigned short* xt     = (unsigned short*)(smem + 32768);  // [64*169]
    unsigned short* h_g    = (unsigned short*)smem;            // [16][256][8]
    unsigned short* w1g    = (unsigned short*)(smem + 65536);  // [8][128][8]
    float*          stage  = (float*)(smem + 65536);           // [16][169]
    float*          b1s    = (float*)(smem + 77824);           // [128]

    const int tid  = threadIdx.x;
    const int wid  = tid >> 6;
    const int lane = tid & 63;
    const int lr   = lane & 15;
    const int hi   = lane >> 4;

    // ---------------- stage w1 -> w1g (bf16, k zero-padded 36->64), b1 -> b1s ----------------
    #pragma unroll
    for (int it = 0; it < 4; ++it) {
        const int idx = tid + it * 256;   // 0..1023 = n*8 + g
        const int n = idx >> 3, g = idx & 7;
        short8 pk;
        #pragma unroll
        for (int j = 0; j < 8; ++j) {
            const int k = g * 8 + j;
            pk[j] = (short)f2bf(k < 36 ? w1[n * 36 + k] : 0.0f);
        }
        *(short8*)(w1g + (g * 128 + n) * 8) = pk;
    }
    if (tid < 128) b1s[tid] = b1[tid];

    // zero-fill pool_g k-groups 4..7 (k >= 32 pad; k=32..35 overwritten below)
    {
        short8 z8 = {0, 0, 0, 0, 0, 0, 0, 0};
        #pragma unroll
        for (int it = 0; it < 8; ++it)
            *(short8*)(pool_g + 8192 + (tid + it * 256) * 8) = z8;
    }

    // ---------------- coalesced pooling: 4 quarters of 64 rows ----------------
    const long blkRowBase = (long)blockIdx.x * 256;
    #pragma unroll 1
    for (int q = 0; q < 4; ++q) {
        // flat coalesced copy: 64 rows x 169 f32 = 2704 float4 -> xt (bf16)
        const float* __restrict__ xsrc = x + (blkRowBase + q * 64) * NF;
        #pragma unroll
        for (int it = 0; it < 11; ++it) {
            const int i = tid + it * 256;
            if (i < 2704) {
                f4a v = *(const f4a*)(xsrc + i * 4);
                uint2v pk;
                pk.x = (unsigned)f2bf(v[0]) | ((unsigned)f2bf(v[1]) << 16);
                pk.y = (unsigned)f2bf(v[2]) | ((unsigned)f2bf(v[3]) << 16);
                *(uint2v*)(xt + i * 4) = pk;
            }
        }
        block_sync_lds();   // xt ready

        // 2304 windows (64 rows x 36) over 256 threads, 9 each
        #pragma unroll
        for (int i = 0; i < 9; ++i) {
            const int idx = tid * 9 + i;        // < 2304
            const int r   = idx / 36;
            const int k   = idx - r * 36;
            const int wi  = k / 6;
            const int wj  = k - wi * 6;
            float s = 0.0f;
            #pragma unroll
            for (int rr = 0; rr < 3; ++rr)
                #pragma unroll
                for (int cc = 0; cc < 3; ++cc) {
                    const int gi = (2 * wi + rr) * 14 + 2 * wj + cc;
                    if (gi < NF) s += bf2f(xt[r * NF + gi]);   // pad region -> 0
                }
            const float p = fmaxf(s * (1.0f / 9.0f), 0.0f);
            const int grow = q * 64 + r;
            pool_g[((k >> 3) * 256 + grow) * 8 + (k & 7)] = f2bf(p);
        }
        block_sync_lds();   // pool rows written; xt dead -> next quarter may overwrite
    }

    // ---------------- A1 fragments + w2/b2 fragments to registers ----------------
    short8 afrag[4][2];
    #pragma unroll
    for (int mt = 0; mt < 4; ++mt)
        #pragma unroll
        for (int ks = 0; ks < 2; ++ks) {
            const int g = ks * 4 + hi;
            afrag[mt][ks] = *(const short8*)(pool_g + (g * 256 + wid * 64 + mt * 16 + lr) * 8);
        }

    const int nOt = (wid < 3) ? 3 : 2;   // ot = wid + 4t, 11 total
    short8 wfrag[3][4];
    float  bias2[3];
    #pragma unroll
    for (int t = 0; t < 3; ++t) {
        const int ot = wid + 4 * t;
        const int o  = ot * 16 + lr;
        const bool valid = (t < nOt) && (o < NF);
        bias2[t] = valid ? b2[o] : 0.0f;
        #pragma unroll
        for (int ks = 0; ks < 4; ++ks) {
            short8 pk = {0, 0, 0, 0, 0, 0, 0, 0};
            if (valid) {
                const float* wp = w2 + o * NH + ks * 32 + hi * 8;
                #pragma unroll
                for (int j = 0; j < 8; ++j) pk[j] = (short)f2bf(wp[j]);
            }
            wfrag[t][ks] = pk;
        }
    }
    block_sync_lds();   // (2) all a-frags read; pool/xt dead -> h_g may overwrite

    // ---------------- GEMM1: h = relu(pooled @ w1^T + b1) -> h_g ----------------
    short8 b1f[8][2];
    #pragma unroll
    for (int nt = 0; nt < 8; ++nt)
        #pragma unroll
        for (int ks = 0; ks < 2; ++ks) {
            const int g = ks * 4 + hi;
            b1f[nt][ks] = *(const short8*)(w1g + (g * 128 + nt * 16 + lr) * 8);
        }
    float bias1[8];
    #pragma unroll
    for (int nt = 0; nt < 8; ++nt) bias1[nt] = b1s[nt * 16 + lr];

    #pragma unroll
    for (int mt = 0; mt < 4; ++mt) {
        #pragma unroll
        for (int nt = 0; nt < 8; ++nt) {
            f32x4 c = {0.f, 0.f, 0.f, 0.f};
            c = MFMA(afrag[mt][0], b1f[nt][0], c);
            c = MFMA(afrag[mt][1], b1f[nt][1], c);
            const int g = 2 * nt + (lr >> 3);
            const int e = lr & 7;
            #pragma unroll
            for (int r = 0; r < 4; ++r) {
                const float v = fmaxf(c[r] + bias1[nt], 0.0f);
                const int rw = wid * 64 + mt * 16 + hi * 4 + r;
                h_g[(g * 256 + rw) * 8 + e] = (unsigned short)f2bf(v);
            }
        }
    }
    block_sync_lds();   // (3) h_g complete; w1g dead -> stage usable

    // ---------------- GEMM2 (ot-split) pipelined: stores overlap next-tile MFMA ----------------
    short8 a2[4];
    f32x4  acc[3];

    #define COMPUTE_ACC(MT) do {                                                   \
        _Pragma("unroll")                                                          \
        for (int ks = 0; ks < 4; ++ks) {                                           \
            const int g = ks * 4 + hi;                                             \
            a2[ks] = *(const short8*)(h_g + (g * 256 + (MT) * 16 + lr) * 8);       \
        }                                                                          \
        _Pragma("unroll")                                                          \
        for (int t = 0; t < 3; ++t) {                                              \
            f32x4 c = {0.f, 0.f, 0.f, 0.f};                                        \
            _Pragma("unroll")                                                      \
            for (int ks = 0; ks < 4; ++ks)                                         \
                c = MFMA(a2[ks], wfrag[t][ks], c);                                 \
            acc[t] = c;                                                            \
        }                                                                          \
    } while (0)

    COMPUTE_ACC(0);
    #pragma unroll 1
    for (int mt = 0; mt < 16; ++mt) {
        // stage this tile's result
        #pragma unroll
        for (int t = 0; t < 3; ++t) {
            const int ot = wid + 4 * t;
            const int o  = ot * 16 + lr;
            if (t < nOt && o < NF) {
                #pragma unroll
                for (int r = 0; r < 4; ++r)
                    stage[(hi * 4 + r) * NF + o] = acc[t][r] + bias2[t];
            }
        }
        block_sync_lds();   // stage complete

        // stores of this tile overlap with next tile's ds_reads + MFMA
        float* op = out + (blkRowBase + mt * 16) * NF;
        #pragma unroll
        for (int it = 0; it < 3; ++it) {
            const int i = tid + it * 256;
            if (i < 676) {
                f32x4 v = *(const f32x4*)(stage + 4 * i);
                *(f32x4*)(op + 4 * i) = v;
            }
        }
        if (mt < 15) COMPUTE_ACC(mt + 1);
        block_sync_lds();   // stage ds_reads drained; stores stay in flight
    }
    #undef COMPUTE_ACC
}

extern "C" void kernel_launch(void* const* d_in, const int* in_sizes, int n_in,
                              void* d_out, int out_size, void* d_ws, size_t ws_size,
                              hipStream_t stream) {
    const float* x  = (const float*)d_in[0];
    const float* w1 = (const float*)d_in[1];
    const float* b1 = (const float*)d_in[2];
    const float* w2 = (const float*)d_in[3];
    const float* b2 = (const float*)d_in[4];
    float* out = (float*)d_out;

    const int rows = in_sizes[0] / NF;      // 131072
    const int blocks = rows / 256;          // 512
    fused_v9<<<blocks, 256, 0, stream>>>(x, w1, b1, w2, b2, out);
}

// Round 10
// 53.024 us; speedup vs baseline: 1.3638x; 1.1273x over previous
//
#include <hip/hip_runtime.h>
#include <hip/hip_bf16.h>

typedef __attribute__((ext_vector_type(8))) short short8;
typedef __attribute__((ext_vector_type(4))) float f32x4;
typedef __attribute__((ext_vector_type(2))) unsigned int uint2v;
typedef float f4a __attribute__((ext_vector_type(4), aligned(4)));

constexpr int NF = 169;
constexpr int NH = 128;
constexpr int R  = 128;   // rows per block

#define MFMA(a, b, c) __builtin_amdgcn_mfma_f32_16x16x32_bf16(a, b, c, 0, 0, 0)

__device__ inline unsigned short f2bf(float f) {
    union { __hip_bfloat16 h; unsigned short u; } c;
    c.h = __float2bfloat16(f);
    return c.u;
}

// Block barrier draining only the LDS pipe (cross-wave deps here are LDS-only;
// global stores stay in flight — no vmcnt drain).
__device__ inline void block_sync_lds() {
    __builtin_amdgcn_sched_barrier(0);
    asm volatile("s_waitcnt lgkmcnt(0)" ::: "memory");
    __builtin_amdgcn_sched_barrier(0);
    __builtin_amdgcn_s_barrier();
    __builtin_amdgcn_sched_barrier(0);
}

// Half-row pooling: H2=0 -> window-rows 0..2 (x[0..98)), H2=1 -> 3..5 (x[84..169)).
// All flocal indices compile-time (wave-uniform H2).
template<int H2>
__device__ inline void pool_half(const float* __restrict__ xr, float* pooled /*[18]*/) {
    constexpr int BASE = 84 * H2;
    float fl[100];
    #pragma unroll
    for (int i = 0; i < 25; ++i) {
        const int e = BASE + 4 * i;
        if (e + 3 < NF) {
            f4a v = *(const f4a*)(xr + e);
            fl[e - BASE + 0] = v[0]; fl[e - BASE + 1] = v[1];
            fl[e - BASE + 2] = v[2]; fl[e - BASE + 3] = v[3];
        } else {
            #pragma unroll
            for (int j = 0; j < 4; ++j) {
                const int g = e + j;
                if (g < NF && g - BASE < 100) fl[g - BASE] = xr[g];
            }
        }
    }
    #pragma unroll
    for (int i6 = 0; i6 < 3; ++i6) {
        const int I = 3 * H2 + i6;           // global window-row
        float cs[13];
        #pragma unroll
        for (int c = 0; c < 13; ++c) {
            float s = 0.0f;
            #pragma unroll
            for (int rr = 0; rr < 3; ++rr) {
                const int g = (2 * I + rr) * 14 + c;   // compile-time
                if (g < NF) s += fl[g - BASE];         // pad -> 0
            }
            cs[c] = s;
        }
        #pragma unroll
        for (int j = 0; j < 6; ++j) {
            const float s = cs[2*j] + cs[2*j+1] + cs[2*j+2];
            pooled[i6 * 6 + j] = fmaxf(s * (1.0f / 9.0f), 0.0f);
        }
    }
}

// LDS map (45568 B, 3 blocks/CU):
//  [0, 32768):      h_g[16][128][8] bf16;  pool_g[8][128][8] aliases [0,16384)
//  [32768, 45056):  w1g[8][128][8] bf16;   stage[16][169] f32 aliases (10816 B)
//  [45056, 45568):  b1s[128] f32
__global__ __launch_bounds__(256, 3) void fused_v10(
    const float* __restrict__ x,
    const float* __restrict__ w1,
    const float* __restrict__ b1,
    const float* __restrict__ w2,
    const float* __restrict__ b2,
    float* __restrict__ out)
{
    __shared__ __align__(16) char smem[45568];
    unsigned short* pool_g = (unsigned short*)smem;            // [8][128][8]
    unsigned short* h_g    = (unsigned short*)smem;            // [16][128][8]
    unsigned short* w1g    = (unsigned short*)(smem + 32768);  // [8][128][8]
    float*          stage  = (float*)(smem + 32768);           // [16][169]
    float*          b1s    = (float*)(smem + 45056);           // [128]

    const int tid  = threadIdx.x;
    const int wid  = tid >> 6;
    const int lane = tid & 63;
    const int lr   = lane & 15;
    const int hi   = lane >> 4;

    // ---------------- stage w1 -> w1g (bf16, k zero-padded 36->64), b1 -> b1s ----------------
    #pragma unroll
    for (int it = 0; it < 4; ++it) {
        const int idx = tid + it * 256;   // 0..1023 = n*8 + g
        const int n = idx >> 3, g = idx & 7;
        short8 pk;
        #pragma unroll
        for (int j = 0; j < 8; ++j) {
            const int k = g * 8 + j;
            pk[j] = (short)f2bf(k < 36 ? w1[n * 36 + k] : 0.0f);
        }
        *(short8*)(w1g + (g * 128 + n) * 8) = pk;
    }
    if (tid < 128) b1s[tid] = b1[tid];

    // ---------------- zero-fill pool_g pad region k=36..63 (dwords 18..31 per row) ----------------
    {
        const short8 z8 = {0, 0, 0, 0, 0, 0, 0, 0};
        const int r0 = tid & 127;
        if (tid < 128) {
            // kg4 upper half (k36..39) + kg5 (k40..47)
            *(uint2v*)(pool_g + (4 * 128 + r0) * 8 + 4) = (uint2v){0u, 0u};
            *(short8*)(pool_g + (5 * 128 + r0) * 8) = z8;
        } else {
            *(short8*)(pool_g + (6 * 128 + r0) * 8) = z8;
            *(short8*)(pool_g + (7 * 128 + r0) * 8) = z8;
        }
    }

    // ---------------- pooling: half-rows, wave-uniform split ----------------
    const long blkRowBase = (long)blockIdx.x * R;
    const int  prow = tid & 127;           // row 0..127
    const float* __restrict__ xr = x + (blkRowBase + prow) * NF;

    float pooled[18];
    if (tid < 128) pool_half<0>(xr, pooled);   // k = 0..17
    else           pool_half<1>(xr, pooled);   // k = 18..35
    const int h2 = tid >> 7;

    // pack to 9 dwords, write at dword d = h2*9 + dd  (kg = d>>2, elem = d&3)
    #pragma unroll
    for (int dd = 0; dd < 9; ++dd) {
        unsigned int pk = (unsigned)f2bf(pooled[2*dd]) | ((unsigned)f2bf(pooled[2*dd+1]) << 16);
        const int d = h2 * 9 + dd;
        *(unsigned int*)(pool_g + ((d >> 2) * 128 + prow) * 8 + (d & 3) * 2) = pk;
    }
    block_sync_lds();   // (1) pool_g complete

    // ---------------- A1 fragments (wave rows wid*32..+32) + w2/b2 frags to regs ----------------
    short8 afrag[2][2];
    #pragma unroll
    for (int mt = 0; mt < 2; ++mt)
        #pragma unroll
        for (int ks = 0; ks < 2; ++ks) {
            const int g = ks * 4 + hi;
            afrag[mt][ks] = *(const short8*)(pool_g + (g * 128 + wid * 32 + mt * 16 + lr) * 8);
        }

    const int nOt = (wid < 3) ? 3 : 2;   // ot = wid + 4t, 11 total
    short8 wfrag[3][4];
    float  bias2[3];
    #pragma unroll
    for (int t = 0; t < 3; ++t) {
        const int ot = wid + 4 * t;
        const int o  = ot * 16 + lr;
        const bool valid = (t < nOt) && (o < NF);
        bias2[t] = valid ? b2[o] : 0.0f;
        #pragma unroll
        for (int ks = 0; ks < 4; ++ks) {
            short8 pk = {0, 0, 0, 0, 0, 0, 0, 0};
            if (valid) {
                const float* wp = w2 + o * NH + ks * 32 + hi * 8;
                #pragma unroll
                for (int j = 0; j < 8; ++j) pk[j] = (short)f2bf(wp[j]);
            }
            wfrag[t][ks] = pk;
        }
    }
    block_sync_lds();   // (2) a-frags read; pool dead -> h_g may overwrite

    // ---------------- GEMM1: h = relu(pooled @ w1^T + b1) -> h_g ----------------
    short8 b1f[8][2];
    #pragma unroll
    for (int nt = 0; nt < 8; ++nt)
        #pragma unroll
        for (int ks = 0; ks < 2; ++ks) {
            const int g = ks * 4 + hi;
            b1f[nt][ks] = *(const short8*)(w1g + (g * 128 + nt * 16 + lr) * 8);
        }
    float bias1[8];
    #pragma unroll
    for (int nt = 0; nt < 8; ++nt) bias1[nt] = b1s[nt * 16 + lr];

    #pragma unroll
    for (int mt = 0; mt < 2; ++mt) {
        #pragma unroll
        for (int nt = 0; nt < 8; ++nt) {
            f32x4 c = {0.f, 0.f, 0.f, 0.f};
            c = MFMA(afrag[mt][0], b1f[nt][0], c);
            c = MFMA(afrag[mt][1], b1f[nt][1], c);
            const int g = 2 * nt + (lr >> 3);
            const int e = lr & 7;
            #pragma unroll
            for (int r = 0; r < 4; ++r) {
                const float v = fmaxf(c[r] + bias1[nt], 0.0f);
                const int rw = wid * 32 + mt * 16 + hi * 4 + r;
                h_g[(g * 128 + rw) * 8 + e] = (unsigned short)f2bf(v);
            }
        }
    }
    block_sync_lds();   // (3) h_g complete; w1g dead -> stage usable

    // ---------------- GEMM2 (ot-split, w2 in regs) + staged coalesced stores ----------------
    #pragma unroll 1
    for (int mt = 0; mt < 8; ++mt) {
        short8 a2[4];
        #pragma unroll
        for (int ks = 0; ks < 4; ++ks) {
            const int g = ks * 4 + hi;
            a2[ks] = *(const short8*)(h_g + (g * 128 + mt * 16 + lr) * 8);
        }
        f32x4 acc[3];
        #pragma unroll
        for (int t = 0; t < 3; ++t) {
            f32x4 c = {0.f, 0.f, 0.f, 0.f};
            #pragma unroll
            for (int ks = 0; ks < 4; ++ks)
                c = MFMA(a2[ks], wfrag[t][ks], c);
            acc[t] = c;
        }
        #pragma unroll
        for (int t = 0; t < 3; ++t) {
            const int ot = wid + 4 * t;
            const int o  = ot * 16 + lr;
            if (t < nOt && o < NF) {
                #pragma unroll
                for (int r = 0; r < 4; ++r)
                    stage[(hi * 4 + r) * NF + o] = acc[t][r] + bias2[t];
            }
        }
        block_sync_lds();   // stage complete

        float* op = out + (blkRowBase + mt * 16) * NF;
        #pragma unroll
        for (int it = 0; it < 3; ++it) {
            const int i = tid + it * 256;
            if (i < 676) {                      // 16*169/4 float4s
                f32x4 v = *(const f32x4*)(stage + 4 * i);
                *(f32x4*)(op + 4 * i) = v;
            }
        }
        block_sync_lds();   // stage ds_reads drained; stores stay in flight
    }
}

extern "C" void kernel_launch(void* const* d_in, const int* in_sizes, int n_in,
                              void* d_out, int out_size, void* d_ws, size_t ws_size,
                              hipStream_t stream) {
    const float* x  = (const float*)d_in[0];
    const float* w1 = (const float*)d_in[1];
    const float* b1 = (const float*)d_in[2];
    const float* w2 = (const float*)d_in[3];
    const float* b2 = (const float*)d_in[4];
    float* out = (float*)d_out;

    const int rows = in_sizes[0] / NF;      // 131072
    const int blocks = rows / R;            // 1024
    fused_v10<<<blocks, 256, 0, stream>>>(x, w1, b1, w2, b2, out);
}